// Round 2
// baseline (372.346 us; speedup 1.0000x reference)
//
#include <hip/hip_runtime.h>
#include <hip/hip_bf16.h>

// Problem constants (from reference setup_inputs)
#define BB 8
#define MM 100
#define NN 32
#define HWSZ 65536           // 256*256
#define IOU_THR 0.5f
#define SCORE_THR 0.0f

// Output layout (concatenated flat, element offsets; dtype f32 or bf16,
// runtime-detected — the f32 path is the live one per earlier benches):
//   gt_masks : BB*NN*HWSZ = 16,777,216
//   flags    : BB*NN      = 256
//   gtm      : BB*NN      = 256
//   biou     : BB*NN      = 256
#define MASKS_ELEMS ((size_t)BB * NN * HWSZ)

// 16-byte vector the nontemporal builtins accept (HIP's uint4 is a struct).
typedef unsigned int u32x4 __attribute__((ext_vector_type(4)));

#define CHUNK_BYTES 32768
#define CHUNKS_PER_MASK 8     // f32: 8 x 32 KiB = 256 KiB; bf16 uses 0..3

// Round f32 -> bf16 (RNE) -> f32 (emulates one bf16 op exactly).
__device__ __forceinline__ float bf16r(float x) {
    unsigned u = __float_as_uint(x);
    u = (u + 0x7FFFu + ((u >> 16) & 1u)) & 0xFFFF0000u;
    return __uint_as_float(u);
}

// ---------------------------------------------------------------------------
// R5: SINGLE fused kernel. Every block owns one (bn, chunk) gather tile and
// REDUNDANTLY recomputes the match for its batch (deterministic, ~16 KiB LDS,
// ~5k cycles, inputs L2-cached across the 256 blocks/batch that share them).
// This removes: the second launch, the match->gather dependency, and all
// d_ws traffic. Grid = BB*NN*8 = 2048 blocks x 256 thr = 8192 waves = exactly
// the 256-CU residency limit.
// ---------------------------------------------------------------------------
__global__ __launch_bounds__(256) void fused_kernel(
    const void* __restrict__ pred_boxes,  // [BB,MM,4]
    const void* __restrict__ gt_boxes,    // [BB,NN,4]
    const void* __restrict__ pred_scores, // [BB,MM]
    const void* __restrict__ pred_masks,  // [BB,MM,H,W]
    const void* __restrict__ mask_score,  // [BB,MM]
    void* __restrict__ out)
{
    const int bid   = blockIdx.x;
    const int bn    = bid >> 3;          // CHUNKS_PER_MASK = 8
    const int chunk = bid & 7;
    const int b     = bn >> 5;           // NN = 32
    const int n     = bn & 31;
    const int t     = threadIdx.x;

    __shared__ float pb[MM][4];
    __shared__ float gb[NN][4];
    __shared__ float sc[MM];
    __shared__ float area2[NN];
    __shared__ float iou_s[MM][NN];   // lane j -> bank j, conflict-free
    __shared__ int   order_s[MM];
    __shared__ int   gtm_lds[NN];
    __shared__ int   flag_s;

    // --- dtype sniff (wave 0): first 2048 B of gt_boxes as 512 u32. If bf16
    // pairs, low 16 bits of each u32 are a plausible coordinate (sign 0,
    // exponent 118..137) ~100%; if f32, uniform mantissa bits (~4%).
    if (t < 64) {
        const unsigned* gt_raw = (const unsigned*)gt_boxes;
        int cnt = 0;
        #pragma unroll
        for (int k = 0; k < 8; ++k) {
            const unsigned u  = gt_raw[t * 8 + k];
            const unsigned lo = u & 0xFFFFu;
            const unsigned ex = (lo >> 7) & 0xFFu;
            if (((lo >> 15) == 0u) && ex >= 118u && ex <= 137u) ++cnt;
        }
        #pragma unroll
        for (int m = 1; m < 64; m <<= 1) cnt += __shfl_xor(cnt, m, 64);
        if (t == 0) flag_s = (cnt >= 256) ? 1 : 0;
    }
    __syncthreads();
    const bool isbf = (flag_s != 0);

    const size_t mbytes = isbf ? (size_t)HWSZ * 2 : (size_t)HWSZ * 4;
    const size_t cbase  = (size_t)chunk * CHUNK_BYTES;
    if (cbase >= mbytes) return;         // bf16 mode: upper chunks idle
                                         // (block-uniform; no barrier after
                                         //  this point is skipped unevenly)

    const __hip_bfloat16* pb_h = (const __hip_bfloat16*)pred_boxes;
    const float*          pb_f = (const float*)pred_boxes;
    const __hip_bfloat16* gb_h = (const __hip_bfloat16*)gt_boxes;
    const float*          gb_f = (const float*)gt_boxes;
    const __hip_bfloat16* sc_h = (const __hip_bfloat16*)pred_scores;
    const float*          sc_f = (const float*)pred_scores;

    for (int i = t; i < MM * 4; i += 256) {
        const size_t o = (size_t)b * MM * 4 + i;
        pb[i >> 2][i & 3] = isbf ? __bfloat162float(pb_h[o]) : pb_f[o];
    }
    for (int i = t; i < NN * 4; i += 256) {
        const size_t o = (size_t)b * NN * 4 + i;
        gb[i >> 2][i & 3] = isbf ? __bfloat162float(gb_h[o]) : gb_f[o];
    }
    for (int i = t; i < MM; i += 256) {
        const size_t o = (size_t)b * MM + i;
        sc[i] = isbf ? __bfloat162float(sc_h[o]) : sc_f[o];
    }
    __syncthreads();

    // rnd(): per-op bf16 rounding in bf16 mode, identity in f32 mode.
    auto rnd = [&](float x) { return isbf ? bf16r(x) : x; };

    if (t < NN)
        area2[t] = rnd(rnd(gb[t][2] - gb[t][0]) * rnd(gb[t][3] - gb[t][1]));
    __syncthreads();

    // IoU matrix — reference op order: inter / ((a1 + a2) - inter)
    for (int e = t; e < MM * NN; e += 256) {
        const int i = e >> 5;          // / NN
        const int j = e & 31;          // % NN
        const float a1 = rnd(rnd(pb[i][2] - pb[i][0]) * rnd(pb[i][3] - pb[i][1]));
        const float lx = fmaxf(pb[i][0], gb[j][0]);
        const float ly = fmaxf(pb[i][1], gb[j][1]);
        const float rx = fminf(pb[i][2], gb[j][2]);
        const float ry = fminf(pb[i][3], gb[j][3]);
        const float w  = fmaxf(rnd(rx - lx), 0.0f);
        const float h  = fmaxf(rnd(ry - ly), 0.0f);
        const float inter = rnd(w * h);
        const float denom = rnd(rnd(a1 + area2[j]) - inter);
        iou_s[i][j] = rnd(inter / denom);
    }

    // Stable descending argsort: rank_i = #{j : s_j > s_i or (s_j==s_i && j<i)}
    // Matches jnp.argsort(-scores) (stable) exactly, including ties.
    if (t < MM) {
        const float si = sc[t];
        int r = 0;
        for (int j = 0; j < MM; ++j) {
            const float sj = sc[j];
            if (sj > si || (sj == si && j < t)) ++r;
        }
        order_s[r] = t;
    }
    __syncthreads();

    // Greedy matching: lanes 0..31, lane j owns gt j.
    if (t < 32) {
        const int j = t;
        int   gtm_j  = -1;
        float biou_j = 0.0f;

        for (int s = 0; s < MM; ++s) {
            const int i = order_s[s];
            const float row = iou_s[i][j];
            // faithful: gt available iff gtm[j] <= 0 (NOT > -1)
            const float cand = (gtm_j <= 0 && row >= IOU_THR) ? row : -1.0f;

            // 32-lane argmax, first-max (lowest j) tie-break == jnp.argmax
            float v  = cand;
            int   vj = j;
            #pragma unroll
            for (int m = 1; m < 32; m <<= 1) {
                const float ov = __shfl_xor(v, m, 32);
                const int   oj = __shfl_xor(vj, m, 32);
                if (ov > v || (ov == v && oj < vj)) { v = ov; vj = oj; }
            }
            const bool doit = (sc[i] >= SCORE_THR) && (v >= IOU_THR);
            if (doit && vj == j) { gtm_j = i; biou_j = v; }
        }

        gtm_lds[j] = gtm_j;

        // Only the chunk-0 block for this bn writes this column's scalars,
        // and only from the lane that owns column n.
        if (chunk == 0 && j == n) {
            const int obn = b * NN + j;
            const bool matched = (gtm_j > -1);
            float fs = 0.0f;
            if (matched) {
                const size_t o = (size_t)b * MM + gtm_j;
                fs = isbf ? __bfloat162float(((const __hip_bfloat16*)mask_score)[o])
                          : ((const float*)mask_score)[o];
            }
            if (isbf) {
                __hip_bfloat16* o = (__hip_bfloat16*)out;
                o[MASKS_ELEMS + obn]       = __float2bfloat16(fs);
                o[MASKS_ELEMS + 256 + obn] = __float2bfloat16((float)gtm_j);
                o[MASKS_ELEMS + 512 + obn] = __float2bfloat16(biou_j);
            } else {
                float* o = (float*)out;
                o[MASKS_ELEMS + obn]       = fs;
                o[MASKS_ELEMS + 256 + obn] = (float)gtm_j;
                o[MASKS_ELEMS + 512 + obn] = biou_j;
            }
        }
    }
    __syncthreads();

    // --- Gather phase: this block's 32 KiB tile of mask (b,n). ---
    const int idx = gtm_lds[n];
    const size_t tb = cbase + (size_t)t * 16;
    char* dst = (char*)out + (size_t)bn * mbytes;

    if (idx > -1) {
        const char* src = (const char*)pred_masks + ((size_t)b * MM + idx) * mbytes;
        u32x4 v[8];
        #pragma unroll
        for (int k = 0; k < 8; ++k)
            v[k] = __builtin_nontemporal_load((const u32x4*)(src + tb + (size_t)k * 4096));
        #pragma unroll
        for (int k = 0; k < 8; ++k)
            __builtin_nontemporal_store(v[k], (u32x4*)(dst + tb + (size_t)k * 4096));
    } else {
        const u32x4 z = (u32x4)0;
        #pragma unroll
        for (int k = 0; k < 8; ++k)
            __builtin_nontemporal_store(z, (u32x4*)(dst + tb + (size_t)k * 4096));
    }
}

extern "C" void kernel_launch(void* const* d_in, const int* in_sizes, int n_in,
                              void* d_out, int out_size, void* d_ws, size_t ws_size,
                              hipStream_t stream) {
    const void* pred_boxes  = d_in[0];
    const void* gt_boxes    = d_in[1];
    const void* pred_scores = d_in[2];
    const void* pred_masks  = d_in[3];
    const void* mask_score  = d_in[4];
    (void)d_ws; (void)ws_size;

    fused_kernel<<<BB * NN * CHUNKS_PER_MASK, 256, 0, stream>>>(
        pred_boxes, gt_boxes, pred_scores, pred_masks, mask_score, d_out);
}

// Round 3
// 276.473 us; speedup vs baseline: 1.3468x; 1.3468x over previous
//
#include <hip/hip_runtime.h>
#include <hip/hip_bf16.h>

// Problem constants (from reference setup_inputs)
#define BB 8
#define MM 100
#define NN 32
#define HWSZ 65536           // 256*256
#define IOU_THR 0.5f
#define SCORE_THR 0.0f

// Output layout (concatenated flat, element offsets; dtype f32 or bf16,
// runtime-detected — the f32 path is the live one per earlier benches):
//   gt_masks : BB*NN*HWSZ = 16,777,216
//   flags    : BB*NN      = 256
//   gtm      : BB*NN      = 256
//   biou     : BB*NN      = 256
#define MASKS_ELEMS ((size_t)BB * NN * HWSZ)

// d_ws layout (ints): [0..255] = gtm scratch, [256] = dtype flag (1 = bf16)
#define WS_FLAG 256

// 16-byte vector the nontemporal builtins accept (HIP's uint4 is a struct).
typedef unsigned int u32x4 __attribute__((ext_vector_type(4)));

// Round f32 -> bf16 (RNE) -> f32 (emulates one bf16 op exactly).
__device__ __forceinline__ float bf16r(float x) {
    unsigned u = __float_as_uint(x);
    u = (u + 0x7FFFu + ((u >> 16) & 1u)) & 0xFFFF0000u;
    return __uint_as_float(u);
}

// ---------------------------------------------------------------------------
// Kernel 1 (R6 redesign): latency-optimized match. One block per batch.
// Changes vs the 322.7 us version:
//  * IoU computed directly into SCORE-SORTED row order as packed u32 keys:
//      key = ((f2u(iou) - f2u(0.5)) << 6) | (32 - j)   if iou >= 0.5 else 0
//    - removes the dependent order_s[] indirection from the greedy loop
//    - argmax becomes 5x (shfl_xor + umax) on u32
//    - tie-break (max iou, then lowest j) is exact: equal iou -> larger 32-j
//    - biou recovered bit-exactly: f2u(biou) = (key>>6) + f2u(0.5)
//  * Rows with NO candidate >= 0.5 cannot change greedy state (all cand=-1
//    -> mx=-1 -> no commit). They are ballot-flagged during the key pass and
//    compacted away; the serial greedy loop runs only over ~30-50 live rows.
// ---------------------------------------------------------------------------
__global__ __launch_bounds__(256) void match_kernel(
    const void* __restrict__ pred_boxes,  // [BB,MM,4]
    const void* __restrict__ gt_boxes,    // [BB,NN,4]
    const void* __restrict__ pred_scores, // [BB,MM]
    const void* __restrict__ mask_score,  // [BB,MM]
    void* __restrict__ out,
    int* __restrict__ ws)
{
    const int b = blockIdx.x;
    const int t = threadIdx.x;

    __shared__ float    pb[MM][4];
    __shared__ float    gb[NN][4];
    __shared__ float    sc[MM];
    __shared__ float    area2[NN];
    __shared__ unsigned key_s[MM][NN];   // sorted-row packed keys
    __shared__ int      order_s[MM];
    __shared__ int      rowflag[MM];     // sorted-row has any candidate
    __shared__ int      clist[MM];       // compacted sorted positions
    __shared__ int      ordc[MM];        // original pred index per live row
    __shared__ float    scoc[MM];        // score per live row
    __shared__ int      cnt_s;
    __shared__ int      flag_s;

    // --- dtype sniff (wave 0): first 2048 B of gt_boxes as 512 u32. If bf16
    // pairs, low 16 bits of each u32 are a plausible coordinate (sign 0,
    // exponent 118..137) ~100%; if f32, uniform mantissa bits (~4%).
    if (t < 64) {
        const unsigned* gt_raw = (const unsigned*)gt_boxes;
        int cnt = 0;
        #pragma unroll
        for (int k = 0; k < 8; ++k) {
            const unsigned u  = gt_raw[t * 8 + k];
            const unsigned lo = u & 0xFFFFu;
            const unsigned ex = (lo >> 7) & 0xFFu;
            if (((lo >> 15) == 0u) && ex >= 118u && ex <= 137u) ++cnt;
        }
        #pragma unroll
        for (int m = 1; m < 64; m <<= 1) cnt += __shfl_xor(cnt, m, 64);
        if (t == 0) {
            flag_s = (cnt >= 256) ? 1 : 0;
            if (b == 0) ws[WS_FLAG] = flag_s;   // publish for gather_kernel
        }
    }
    __syncthreads();
    const bool isbf = (flag_s != 0);

    const __hip_bfloat16* pb_h = (const __hip_bfloat16*)pred_boxes;
    const float*          pb_f = (const float*)pred_boxes;
    const __hip_bfloat16* gb_h = (const __hip_bfloat16*)gt_boxes;
    const float*          gb_f = (const float*)gt_boxes;
    const __hip_bfloat16* sc_h = (const __hip_bfloat16*)pred_scores;
    const float*          sc_f = (const float*)pred_scores;

    for (int i = t; i < MM * 4; i += 256) {
        const size_t o = (size_t)b * MM * 4 + i;
        pb[i >> 2][i & 3] = isbf ? __bfloat162float(pb_h[o]) : pb_f[o];
    }
    for (int i = t; i < NN * 4; i += 256) {
        const size_t o = (size_t)b * NN * 4 + i;
        gb[i >> 2][i & 3] = isbf ? __bfloat162float(gb_h[o]) : gb_f[o];
    }
    for (int i = t; i < MM; i += 256) {
        const size_t o = (size_t)b * MM + i;
        sc[i] = isbf ? __bfloat162float(sc_h[o]) : sc_f[o];
    }
    __syncthreads();

    // rnd(): per-op bf16 rounding in bf16 mode, identity in f32 mode.
    auto rnd = [&](float x) { return isbf ? bf16r(x) : x; };

    // gt areas (threads 0..31) and stable argsort ranks (threads 0..99),
    // both only need the loaded sc/gb.
    if (t < NN)
        area2[t] = rnd(rnd(gb[t][2] - gb[t][0]) * rnd(gb[t][3] - gb[t][1]));

    // Stable descending argsort: rank_i = #{j : s_j > s_i or (s_j==s_i && j<i)}
    // Matches jnp.argsort(-scores) (stable) exactly, including ties.
    if (t < MM) {
        const float si = sc[t];
        int r = 0;
        for (int j = 0; j < MM; ++j) {
            const float sj = sc[j];
            if (sj > si || (sj == si && j < t)) ++r;
        }
        order_s[r] = t;
    }
    __syncthreads();

    // IoU -> packed keys in sorted-row order; reference op order preserved:
    // inter / ((a1 + a2) - inter). Row flags via per-wave ballot (each row's
    // 32 elements live in one half of one wave; lane j==0 publishes).
    for (int e = t; e < MM * NN; e += 256) {
        const int s = e >> 5;          // sorted position
        const int j = e & 31;          // gt column
        const int i = order_s[s];      // original pred row
        const float a1 = rnd(rnd(pb[i][2] - pb[i][0]) * rnd(pb[i][3] - pb[i][1]));
        const float lx = fmaxf(pb[i][0], gb[j][0]);
        const float ly = fmaxf(pb[i][1], gb[j][1]);
        const float rx = fminf(pb[i][2], gb[j][2]);
        const float ry = fminf(pb[i][3], gb[j][3]);
        const float w  = fmaxf(rnd(rx - lx), 0.0f);
        const float h  = fmaxf(rnd(ry - ly), 0.0f);
        const float inter = rnd(w * h);
        const float denom = rnd(rnd(a1 + area2[j]) - inter);
        const float iou   = rnd(inter / denom);
        // iou >= 0.5 (false for NaN, same as reference's >= compare) ->
        // f2u(iou) in [0x3F000000, 0x3F800000] -> 24-bit delta, 6-bit lane tag.
        unsigned key = 0u;
        if (iou >= IOU_THR)
            key = ((__float_as_uint(iou) - 0x3F000000u) << 6) | (32u - (unsigned)j);
        key_s[s][j] = key;
        const unsigned long long m = __ballot(key != 0u);
        if (j == 0)   // first element of this row within the wave
            rowflag[s] = ((unsigned)(m >> (t & 32)) != 0u) ? 1 : 0;
    }
    __syncthreads();

    // Compact live rows (prefix sum over 100 flags, O(M) per thread).
    if (t < MM) {
        int r = 0;
        for (int u = 0; u < t; ++u) r += rowflag[u];
        if (rowflag[t]) {
            clist[r] = t;
            const int i = order_s[t];
            ordc[r] = i;
            scoc[r] = sc[i];
        }
        if (t == MM - 1) cnt_s = r + rowflag[t];
    }
    __syncthreads();

    // Greedy matching over live rows only: lanes 0..31, lane j owns gt j.
    // Loop-carried state is ONLY gtm_j; all LDS reads are p-indexed and
    // pipeline across iterations.
    if (t < 32) {
        const int j = t;
        int   gtm_j  = -1;
        float biou_j = 0.0f;
        const int cnt = cnt_s;

        for (int p = 0; p < cnt; ++p) {
            const int s = clist[p];
            const unsigned key = key_s[s][j];
            // faithful: gt available iff gtm[j] <= 0 (NOT > -1)
            unsigned k = (gtm_j <= 0) ? key : 0u;
            unsigned v = k;
            #pragma unroll
            for (int m = 1; m < 32; m <<= 1) {
                const unsigned ov = __shfl_xor(v, m, 32);
                v = (ov > v) ? ov : v;
            }
            // v==0 -> no available candidate >= THR for this row (mx < THR).
            // Winner lane is unique (keys carry distinct lane tags).
            if (v != 0u && scoc[p] >= SCORE_THR && k == v) {
                gtm_j  = ordc[p];
                biou_j = __uint_as_float((v >> 6) + 0x3F000000u);
            }
        }

        const int bn = b * NN + j;
        const bool matched = (gtm_j > -1);
        float fs = 0.0f;
        if (matched) {
            const size_t o = (size_t)b * MM + gtm_j;
            fs = isbf ? __bfloat162float(((const __hip_bfloat16*)mask_score)[o])
                      : ((const float*)mask_score)[o];
        }
        if (isbf) {
            __hip_bfloat16* o = (__hip_bfloat16*)out;
            o[MASKS_ELEMS + bn]       = __float2bfloat16(fs);
            o[MASKS_ELEMS + 256 + bn] = __float2bfloat16((float)gtm_j);
            o[MASKS_ELEMS + 512 + bn] = __float2bfloat16(biou_j);
        } else {
            float* o = (float*)out;
            o[MASKS_ELEMS + bn]       = fs;
            o[MASKS_ELEMS + 256 + bn] = (float)gtm_j;
            o[MASKS_ELEMS + 512 + bn] = biou_j;
        }
        ws[bn] = gtm_j;
    }
}

// ---------------------------------------------------------------------------
// Kernel 2: mask gather/zero, byte-addressed for both dtypes. Verified at
// 322.7 us config: 32 KiB per block, 8 x uint4 per thread, nontemporal both
// directions (both streams touch-once), loads batched before stores.
// ---------------------------------------------------------------------------
#define CHUNK_BYTES 32768
#define CHUNKS_PER_MASK 8     // f32: 8 x 32 KiB = 256 KiB; bf16 uses 0..3

__global__ __launch_bounds__(256) void gather_kernel(
    const void* __restrict__ pred_masks,
    const int* __restrict__ ws,
    void* __restrict__ out)
{
    const bool isbf = (ws[WS_FLAG] != 0);
    const int bn    = blockIdx.x >> 3;          // CHUNKS_PER_MASK = 8
    const int chunk = blockIdx.x & 7;
    const size_t mbytes = isbf ? (size_t)HWSZ * 2 : (size_t)HWSZ * 4;

    const size_t cbase = (size_t)chunk * CHUNK_BYTES;
    if (cbase >= mbytes) return;                // bf16 mode: upper chunks idle

    const int idx = ws[bn];
    const int b   = bn >> 5;                    // NN = 32

    const size_t tb = cbase + (size_t)threadIdx.x * 16;
    char* dst = (char*)out + (size_t)bn * mbytes;

    if (idx > -1) {
        const char* src = (const char*)pred_masks + ((size_t)b * MM + idx) * mbytes;
        u32x4 v[8];
        #pragma unroll
        for (int k = 0; k < 8; ++k)
            v[k] = __builtin_nontemporal_load((const u32x4*)(src + tb + (size_t)k * 4096));
        #pragma unroll
        for (int k = 0; k < 8; ++k)
            __builtin_nontemporal_store(v[k], (u32x4*)(dst + tb + (size_t)k * 4096));
    } else {
        const u32x4 z = (u32x4)0;
        #pragma unroll
        for (int k = 0; k < 8; ++k)
            __builtin_nontemporal_store(z, (u32x4*)(dst + tb + (size_t)k * 4096));
    }
}

extern "C" void kernel_launch(void* const* d_in, const int* in_sizes, int n_in,
                              void* d_out, int out_size, void* d_ws, size_t ws_size,
                              hipStream_t stream) {
    const void* pred_boxes  = d_in[0];
    const void* gt_boxes    = d_in[1];
    const void* pred_scores = d_in[2];
    const void* pred_masks  = d_in[3];
    const void* mask_score  = d_in[4];
    int* ws = (int*)d_ws;

    match_kernel<<<BB, 256, 0, stream>>>(pred_boxes, gt_boxes, pred_scores,
                                         mask_score, d_out, ws);
    gather_kernel<<<BB * NN * CHUNKS_PER_MASK, 256, 0, stream>>>(pred_masks, ws, d_out);
}